// Round 7
// baseline (582.489 us; speedup 1.0000x reference)
//
#include <hip/hip_runtime.h>

#define DEVINL __device__ __forceinline__

// LDS-tiled GEMM: out[n, 0:128] = x[n, 0:K] @ [Wa | Wb], split back into
// oa[n,0:64], ob[n,0:64]. Block = 256 threads -> 64-node x 128-col tile.
// Thread owns 8 nodes x 4 cols = 32 accumulators.
template <int K>
__global__ void k_lin_tiled(const float* __restrict__ x,
                            const float* __restrict__ Wa,
                            const float* __restrict__ Wb,
                            float* __restrict__ oa, float* __restrict__ ob,
                            int N) {
    __shared__ float sx[64 * K];     // x tile, row-major [64][K]
    __shared__ float sw[K * 128];    // [K][128] = [K][Wa|Wb]
    int t = threadIdx.x;
    int base = blockIdx.x * 64;

    // stage W (both matrices), coalesced float4
    const int WTOT = K * 64 / 4;     // float4s per matrix
    for (int i = t; i < WTOT; i += 256) {
        float4 wa = ((const float4*)Wa)[i];
        float4 wb = ((const float4*)Wb)[i];
        int k = (i * 4) >> 6, f = (i * 4) & 63;
        *(float4*)&sw[k * 128 + f] = wa;
        *(float4*)&sw[k * 128 + 64 + f] = wb;
    }
    // stage x tile, coalesced float4, no transpose
    const int XTOT = 64 * K / 4;
    for (int i = t; i < XTOT; i += 256) {
        int n = (i * 4) / K, kk = (i * 4) % K;
        float4 v = make_float4(0.f, 0.f, 0.f, 0.f);
        if (base + n < N) v = *(const float4*)&x[(size_t)(base + n) * K + kk];
        *(float4*)&sx[n * K + kk] = v;
    }
    __syncthreads();

    int fq = t & 31;    // col group: cols fq*4 .. fq*4+3 of [Wa|Wb]
    int nq = t >> 5;    // node group: nodes nq*8 .. nq*8+7
    float acc[8][4];
#pragma unroll
    for (int i = 0; i < 8; ++i)
#pragma unroll
        for (int c = 0; c < 4; ++c) acc[i][c] = 0.f;

    for (int k0 = 0; k0 < K; k0 += 4) {
        float4 xv[8];
#pragma unroll
        for (int i = 0; i < 8; ++i)
            xv[i] = *(const float4*)&sx[(nq * 8 + i) * K + k0];
#pragma unroll
        for (int kk = 0; kk < 4; ++kk) {
            float4 w = *(const float4*)&sw[(k0 + kk) * 128 + fq * 4];
#pragma unroll
            for (int i = 0; i < 8; ++i) {
                float xs = (kk == 0) ? xv[i].x : (kk == 1) ? xv[i].y
                         : (kk == 2) ? xv[i].z : xv[i].w;
                acc[i][0] = fmaf(xs, w.x, acc[i][0]);
                acc[i][1] = fmaf(xs, w.y, acc[i][1]);
                acc[i][2] = fmaf(xs, w.z, acc[i][2]);
                acc[i][3] = fmaf(xs, w.w, acc[i][3]);
            }
        }
    }

    int col = fq * 4;
    float* o = (col < 64) ? oa : ob;
    int c = col & 63;
#pragma unroll
    for (int i = 0; i < 8; ++i) {
        int n = base + nq * 8 + i;
        if (n < N)
            *(float4*)&o[(size_t)n * 64 + c] =
                make_float4(acc[i][0], acc[i][1], acc[i][2], acc[i][3]);
    }
}

// ---- CSR build ----
__global__ void k_deg(const int* __restrict__ dst, int* __restrict__ deg, int E) {
    int e = blockIdx.x * blockDim.x + threadIdx.x;
    if (e < E) atomicAdd(&deg[dst[e]], 1);
}

__global__ void k_scan1(const int* __restrict__ deg, int* __restrict__ spart,
                        int* __restrict__ bsum, int N) {
    __shared__ int sh[256];
    int base = blockIdx.x * 1024;
    int t = threadIdx.x;
    int v[4]; int sum = 0;
#pragma unroll
    for (int i = 0; i < 4; ++i) {
        int idx = base + t * 4 + i;
        v[i] = (idx < N) ? deg[idx] : 0;
        sum += v[i];
    }
    sh[t] = sum;
    __syncthreads();
    for (int off = 1; off < 256; off <<= 1) {
        int x = (t >= off) ? sh[t - off] : 0;
        __syncthreads();
        sh[t] += x;
        __syncthreads();
    }
    int run = (t > 0) ? sh[t - 1] : 0;
#pragma unroll
    for (int i = 0; i < 4; ++i) {
        run += v[i];
        int idx = base + t * 4 + i;
        if (idx < N) spart[idx] = run;
    }
    if (t == 255) bsum[blockIdx.x] = sh[255];
}

__global__ void k_scan2(int* __restrict__ bsum, int nb) {
    __shared__ int sh[128];
    int t = threadIdx.x;
    sh[t] = (t < nb) ? bsum[t] : 0;
    __syncthreads();
    for (int off = 1; off < 128; off <<= 1) {
        int x = (t >= off) ? sh[t - off] : 0;
        __syncthreads();
        sh[t] += x;
        __syncthreads();
    }
    if (t < nb) bsum[t] = (t > 0) ? sh[t - 1] : 0;
}

__global__ void k_scan3(const int* __restrict__ spart, const int* __restrict__ bsum,
                        int* __restrict__ rowptr, int N) {
    int i = blockIdx.x * blockDim.x + threadIdx.x;
    if (i < N) rowptr[i + 1] = spart[i] + bsum[i >> 10];
    if (i == 0) rowptr[0] = 0;
}

// Scatter edges into CSR order; permute edge_attr along for sequential reads.
__global__ void k_scatter(const int* __restrict__ src, const int* __restrict__ dst,
                          const float4* __restrict__ ea,
                          const int* __restrict__ rowptr, int* __restrict__ fill,
                          int* __restrict__ csr_src, float4* __restrict__ csr_ea, int E) {
    int e = blockIdx.x * blockDim.x + threadIdx.x;
    if (e >= E) return;
    int d = dst[e];
    int pos = rowptr[d] + atomicAdd(&fill[d], 1);
    csr_src[pos] = src[e];
    csr_ea[pos] = ea[e];
}

// Per-edge logit (log2 domain) + gather of this thread's xl feature.
DEVINL float edge_logit(int s, float4 a, float xrv,
                        float w0, float w1, float w2, float w3, float av2,
                        const float* __restrict__ xl, int t, float& xlv) {
    xlv = xl[(size_t)s * 64 + t];
    float ef = fmaf(a.x, w0, fmaf(a.y, w1, fmaf(a.z, w2, a.w * w3)));
    float v = xlv + xrv + ef;
    v = (v >= 0.f) ? v : 0.2f * v;          // LeakyReLU(0.2)
    float pv = v * av2;                      // att * log2(e) folded in
    pv += __shfl_xor(pv, 8, 16);
    pv += __shfl_xor(pv, 4, 16);
    pv += __shfl_xor(pv, 2, 16);
    pv += __shfl_xor(pv, 1, 16);
    return pv;                               // per-head logit, log2 domain
}

// Fused GATv2 logits + segment-softmax + aggregation, node-parallel.
__global__ void k_gat_agg(const int* __restrict__ rowptr,
                          const int* __restrict__ csr_src,
                          const float4* __restrict__ csr_ea,
                          const float* __restrict__ xl,   // [N,64]
                          const float* __restrict__ xr,   // [N,64]
                          const float* __restrict__ We,   // [4,64]
                          const float* __restrict__ att,  // [64]
                          const float* __restrict__ bias, // [64]
                          float* __restrict__ out,        // [N,64]
                          int N, int elu) {
    int t = threadIdx.x & 63;
    int n = blockIdx.x * 4 + (threadIdx.x >> 6);
    if (n >= N) return;
    float w0 = We[t], w1 = We[64 + t], w2 = We[128 + t], w3 = We[192 + t];
    float av2 = att[t] * 1.44269504088896f;   // log2(e)
    float xrv = xr[(size_t)n * 64 + t];
    int beg = rowptr[n], end = rowptr[n + 1];

    float val;
    if (beg == end) {
        val = 0.f;
    } else {
        float xlv0;
        float m = edge_logit(csr_src[beg], csr_ea[beg], xrv, w0, w1, w2, w3, av2, xl, t, xlv0);
        float denom = 1.f, acc = xlv0;
        int j = beg + 1;
        for (; j + 1 < end; j += 2) {
            int s0 = csr_src[j], s1 = csr_src[j + 1];
            float4 a0 = csr_ea[j], a1 = csr_ea[j + 1];
            float x0, x1;
            float p0 = edge_logit(s0, a0, xrv, w0, w1, w2, w3, av2, xl, t, x0);
            float p1 = edge_logit(s1, a1, xrv, w0, w1, w2, w3, av2, xl, t, x1);
            if (__any(fmaxf(p0, p1) - m > 8.f)) {
                float mn = fmaxf(m, fmaxf(p0, p1));
                float sc = exp2f(m - mn);
                float e0 = exp2f(p0 - mn), e1 = exp2f(p1 - mn);
                denom = denom * sc + e0 + e1;
                acc = fmaf(acc, sc, fmaf(e0, x0, e1 * x1));
                m = mn;
            } else {
                float e0 = exp2f(p0 - m), e1 = exp2f(p1 - m);
                denom += e0 + e1;
                acc = fmaf(e0, x0, fmaf(e1, x1, acc));
            }
        }
        if (j < end) {
            float x0;
            float p0 = edge_logit(csr_src[j], csr_ea[j], xrv, w0, w1, w2, w3, av2, xl, t, x0);
            if (__any(p0 - m > 8.f)) {
                float mn = fmaxf(m, p0);
                float sc = exp2f(m - mn);
                float e0 = exp2f(p0 - mn);
                denom = denom * sc + e0;
                acc = fmaf(acc, sc, e0 * x0);
                m = mn;
            } else {
                float e0 = exp2f(p0 - m);
                denom += e0;
                acc = fmaf(e0, x0, acc);
            }
        }
        val = acc / denom;
    }
    val += bias[t];
    if (elu) val = (val > 0.f) ? val : expm1f(val);
    out[(size_t)n * 64 + t] = val;
}

// Run-length accumulating pool.
__global__ void k_pool(const float* __restrict__ y2,
                       const int* __restrict__ batch,
                       float* __restrict__ pool, float* __restrict__ cnt, int N) {
    const int CH = 256;
    int f = threadIdx.x & 63;
    int lane = threadIdx.x >> 6;          // 0..3
    int base = blockIdx.x * CH;
    int curg = -1;
    float acc = 0.f;
    float c = 0.f;
    for (int n = base + lane; n < base + CH && n < N; n += 4) {
        int g = batch[n];
        if (g != curg) {
            if (curg >= 0) {
                atomicAdd(pool + (size_t)curg * 64 + f, acc);
                if (f == 0) atomicAdd(cnt + curg, c);
            }
            curg = g; acc = 0.f; c = 0.f;
        }
        acc += y2[(size_t)n * 64 + f];
        c += 1.f;
    }
    if (curg >= 0) {
        atomicAdd(pool + (size_t)curg * 64 + f, acc);
        if (f == 0) atomicAdd(cnt + curg, c);
    }
}

// One block (64 threads) per graph: mean, 3 MLP heads.
__global__ void k_head(const float* __restrict__ pool, const float* __restrict__ cnt,
                       const float* __restrict__ Wg1, const float* __restrict__ bg1,
                       const float* __restrict__ Wg2, const float* __restrict__ bg2,
                       const float* __restrict__ Wp, const float* __restrict__ bp,
                       const float* __restrict__ Wc1, const float* __restrict__ bc1,
                       const float* __restrict__ Wc2, const float* __restrict__ bc2,
                       float* __restrict__ out) {
    int g = blockIdx.x, f = threadIdx.x;
    __shared__ float sg[64];
    __shared__ float sh[64];
    float inv = 1.f / fmaxf(cnt[g], 1.f);
    sg[f] = pool[(size_t)g * 64 + f] * inv;
    __syncthreads();
    float acc = bg1[f];
    for (int k = 0; k < 64; ++k) acc += sg[k] * Wg1[k * 64 + f];
    sh[f] = fmaxf(acc, 0.f);
    __syncthreads();
    if (f < 15) {
        float o = bg2[f];
        for (int k = 0; k < 64; ++k) o += sh[k] * Wg2[k * 15 + f];
        out[(size_t)g * 15 + f] = o;
    }
    if (f < 10) {
        float o = bp[f];
        for (int k = 0; k < 64; ++k) o += sg[k] * Wp[k * 10 + f];
        out[960 + (size_t)g * 10 + f] = o;
    }
    __syncthreads();
    float acc2 = bc1[f];
    for (int k = 0; k < 64; ++k) acc2 += sg[k] * Wc1[k * 64 + f];
    sh[f] = fmaxf(acc2, 0.f);
    __syncthreads();
    if (f == 0) {
        float v = bc2[0];
        for (int k = 0; k < 64; ++k) v += sh[k] * Wc2[k];
        out[1600 + g] = v;
    }
}

extern "C" void kernel_launch(void* const* d_in, const int* in_sizes, int n_in,
                              void* d_out, int out_size, void* d_ws, size_t ws_size,
                              hipStream_t stream) {
    const float* x     = (const float*)d_in[0];
    const int*   ei    = (const int*)d_in[1];
    const float* ea    = (const float*)d_in[2];
    const int*   batch = (const int*)d_in[3];
    const float* Wl1 = (const float*)d_in[4];
    const float* Wr1 = (const float*)d_in[5];
    const float* We1 = (const float*)d_in[6];
    const float* att1 = (const float*)d_in[7];
    const float* b1  = (const float*)d_in[8];
    const float* Wl2 = (const float*)d_in[9];
    const float* Wr2 = (const float*)d_in[10];
    const float* We2 = (const float*)d_in[11];
    const float* att2 = (const float*)d_in[12];
    const float* b2  = (const float*)d_in[13];
    const float* Wg1 = (const float*)d_in[14];
    const float* bg1 = (const float*)d_in[15];
    const float* Wg2 = (const float*)d_in[16];
    const float* bg2 = (const float*)d_in[17];
    const float* Wp  = (const float*)d_in[18];
    const float* bp  = (const float*)d_in[19];
    const float* Wc1 = (const float*)d_in[20];
    const float* bc1 = (const float*)d_in[21];
    const float* Wc2 = (const float*)d_in[22];
    const float* bc2 = (const float*)d_in[23];

    const int N = in_sizes[0] / 16;       // 100000
    const int E = in_sizes[2] / 4;        // 1600000
    const int* src = ei;
    const int* dst = ei + E;

    // workspace layout (floats)
    float* ws = (float*)d_ws;
    size_t NF = (size_t)N * 64;
    float* A  = ws;                       // xl1, later xr2
    float* B  = A + NF;                   // xr1, later xl2
    float* C  = B + NF;                   // y1, later y2
    float4* csr_ea = (float4*)(C + NF);   // [E] permuted edge_attr
    int* csr_src = (int*)(csr_ea + E);    // [E]
    int* rowptr  = csr_src + E;           // N+1
    int* deg     = rowptr + (N + 1);      // N (reused as fill)
    int* spart   = deg + N;               // N
    int* bsum    = spart + N;             // 128
    float* PL    = (float*)(bsum + 128);  // [64,64]
    float* CT    = PL + 64 * 64;          // [64]

    dim3 blk(256);
    int gE  = (E + 255) / 256;
    int gN  = (N + 255) / 256;
    int nb1 = (N + 1023) / 1024;
    int gAgg = (N + 3) / 4;
    int gLin = (N + 63) / 64;

    // ---- CSR build (shared by both layers) ----
    hipMemsetAsync(deg, 0, (size_t)N * sizeof(int), stream);
    k_deg<<<gE, blk, 0, stream>>>(dst, deg, E);
    k_scan1<<<nb1, blk, 0, stream>>>(deg, spart, bsum, N);
    k_scan2<<<1, 128, 0, stream>>>(bsum, nb1);
    k_scan3<<<gN, blk, 0, stream>>>(spart, bsum, rowptr, N);
    hipMemsetAsync(deg, 0, (size_t)N * sizeof(int), stream);  // reuse as fill
    k_scatter<<<gE, blk, 0, stream>>>(src, dst, (const float4*)ea, rowptr, deg,
                                      csr_src, csr_ea, E);

    // ---- Layer 1 ----
    k_lin_tiled<16><<<gLin, blk, 0, stream>>>(x, Wl1, Wr1, A, B, N);
    k_gat_agg<<<gAgg, blk, 0, stream>>>(rowptr, csr_src, csr_ea, A, B, We1, att1,
                                        b1, C, N, 1);

    // ---- Layer 2 ---- (xl2 -> B, xr2 -> A)
    k_lin_tiled<64><<<gLin, blk, 0, stream>>>(C, Wl2, Wr2, B, A, N);
    k_gat_agg<<<gAgg, blk, 0, stream>>>(rowptr, csr_src, csr_ea, B, A, We2, att2,
                                        b2, C, N, 0);

    // ---- Pool + heads ----
    hipMemsetAsync(PL, 0, (64 * 64 + 64) * sizeof(float), stream);
    k_pool<<<(N + 255) / 256, blk, 0, stream>>>(C, batch, PL, CT, N);
    k_head<<<64, 64, 0, stream>>>(PL, CT, Wg1, bg1, Wg2, bg2, Wp, bp,
                                  Wc1, bc1, Wc2, bc2, (float*)d_out);
}

// Round 8
// 567.482 us; speedup vs baseline: 1.0264x; 1.0264x over previous
//
#include <hip/hip_runtime.h>

#define DEVINL __device__ __forceinline__

#if __has_builtin(__builtin_amdgcn_exp2f)
DEVINL float fexp2(float x) { return __builtin_amdgcn_exp2f(x); }
#else
DEVINL float fexp2(float x) { return exp2f(x); }
#endif

// Reduce-to-all over each 16-lane group via ds_swizzle XOR (BitMode imm):
// offset = (xor<<10) | 0x1F. Single DS op per step, no VALU address math.
DEVINL float red16(float pv) {
    pv += __int_as_float(__builtin_amdgcn_ds_swizzle(__float_as_int(pv), 0x041F));
    pv += __int_as_float(__builtin_amdgcn_ds_swizzle(__float_as_int(pv), 0x081F));
    pv += __int_as_float(__builtin_amdgcn_ds_swizzle(__float_as_int(pv), 0x101F));
    pv += __int_as_float(__builtin_amdgcn_ds_swizzle(__float_as_int(pv), 0x201F));
    return pv;
}

// LDS-tiled GEMM: out[n, 0:128] = x[n, 0:K] @ [Wa | Wb].
template <int K>
__global__ void k_lin_tiled(const float* __restrict__ x,
                            const float* __restrict__ Wa,
                            const float* __restrict__ Wb,
                            float* __restrict__ oa, float* __restrict__ ob,
                            int N) {
    __shared__ float sx[64 * K];
    __shared__ float sw[K * 128];
    int t = threadIdx.x;
    int base = blockIdx.x * 64;

    const int WTOT = K * 64 / 4;
    for (int i = t; i < WTOT; i += 256) {
        float4 wa = ((const float4*)Wa)[i];
        float4 wb = ((const float4*)Wb)[i];
        int k = (i * 4) >> 6, f = (i * 4) & 63;
        *(float4*)&sw[k * 128 + f] = wa;
        *(float4*)&sw[k * 128 + 64 + f] = wb;
    }
    const int XTOT = 64 * K / 4;
    for (int i = t; i < XTOT; i += 256) {
        int n = (i * 4) / K, kk = (i * 4) % K;
        float4 v = make_float4(0.f, 0.f, 0.f, 0.f);
        if (base + n < N) v = *(const float4*)&x[(size_t)(base + n) * K + kk];
        *(float4*)&sx[n * K + kk] = v;
    }
    __syncthreads();

    int fq = t & 31;
    int nq = t >> 5;
    float acc[8][4];
#pragma unroll
    for (int i = 0; i < 8; ++i)
#pragma unroll
        for (int c = 0; c < 4; ++c) acc[i][c] = 0.f;

    for (int k0 = 0; k0 < K; k0 += 4) {
        float4 xv[8];
#pragma unroll
        for (int i = 0; i < 8; ++i)
            xv[i] = *(const float4*)&sx[(nq * 8 + i) * K + k0];
#pragma unroll
        for (int kk = 0; kk < 4; ++kk) {
            float4 w = *(const float4*)&sw[(k0 + kk) * 128 + fq * 4];
#pragma unroll
            for (int i = 0; i < 8; ++i) {
                float xs = (kk == 0) ? xv[i].x : (kk == 1) ? xv[i].y
                         : (kk == 2) ? xv[i].z : xv[i].w;
                acc[i][0] = fmaf(xs, w.x, acc[i][0]);
                acc[i][1] = fmaf(xs, w.y, acc[i][1]);
                acc[i][2] = fmaf(xs, w.z, acc[i][2]);
                acc[i][3] = fmaf(xs, w.w, acc[i][3]);
            }
        }
    }

    int col = fq * 4;
    float* o = (col < 64) ? oa : ob;
    int c = col & 63;
#pragma unroll
    for (int i = 0; i < 8; ++i) {
        int n = base + nq * 8 + i;
        if (n < N)
            *(float4*)&o[(size_t)n * 64 + c] =
                make_float4(acc[i][0], acc[i][1], acc[i][2], acc[i][3]);
    }
}

// ---- CSR build ----
__global__ void k_deg(const int* __restrict__ dst, int* __restrict__ deg, int E) {
    int e = blockIdx.x * blockDim.x + threadIdx.x;
    if (e < E) atomicAdd(&deg[dst[e]], 1);
}

__global__ void k_scan1(const int* __restrict__ deg, int* __restrict__ spart,
                        int* __restrict__ bsum, int N) {
    __shared__ int sh[256];
    int base = blockIdx.x * 1024;
    int t = threadIdx.x;
    int v[4]; int sum = 0;
#pragma unroll
    for (int i = 0; i < 4; ++i) {
        int idx = base + t * 4 + i;
        v[i] = (idx < N) ? deg[idx] : 0;
        sum += v[i];
    }
    sh[t] = sum;
    __syncthreads();
    for (int off = 1; off < 256; off <<= 1) {
        int x = (t >= off) ? sh[t - off] : 0;
        __syncthreads();
        sh[t] += x;
        __syncthreads();
    }
    int run = (t > 0) ? sh[t - 1] : 0;
#pragma unroll
    for (int i = 0; i < 4; ++i) {
        run += v[i];
        int idx = base + t * 4 + i;
        if (idx < N) spart[idx] = run;
    }
    if (t == 255) bsum[blockIdx.x] = sh[255];
}

__global__ void k_scan2(int* __restrict__ bsum, int nb) {
    __shared__ int sh[128];
    int t = threadIdx.x;
    sh[t] = (t < nb) ? bsum[t] : 0;
    __syncthreads();
    for (int off = 1; off < 128; off <<= 1) {
        int x = (t >= off) ? sh[t - off] : 0;
        __syncthreads();
        sh[t] += x;
        __syncthreads();
    }
    if (t < nb) bsum[t] = (t > 0) ? sh[t - 1] : 0;
}

__global__ void k_scan3(const int* __restrict__ spart, const int* __restrict__ bsum,
                        int* __restrict__ rowptr, int N) {
    int i = blockIdx.x * blockDim.x + threadIdx.x;
    if (i < N) rowptr[i + 1] = spart[i] + bsum[i >> 10];
    if (i == 0) rowptr[0] = 0;
}

__global__ void k_scatter(const int* __restrict__ src, const int* __restrict__ dst,
                          const float4* __restrict__ ea,
                          const int* __restrict__ rowptr, int* __restrict__ fill,
                          int* __restrict__ csr_src, float4* __restrict__ csr_ea, int E) {
    int e = blockIdx.x * blockDim.x + threadIdx.x;
    if (e >= E) return;
    int d = dst[e];
    int pos = rowptr[d] + atomicAdd(&fill[d], 1);
    csr_src[pos] = src[e];
    csr_ea[pos] = ea[e];
}

// Per-edge logit (log2 domain) + gather of this thread's xl feature.
// xl_t = xl + t (hoisted); 32-bit voffset addressing.
DEVINL float edge_logit(int s, float4 a, float xrv,
                        float w0, float w1, float w2, float w3, float av2,
                        const float* __restrict__ xl_t, float& xlv) {
    xlv = xl_t[(unsigned)s << 6];
    float ef = fmaf(a.x, w0, fmaf(a.y, w1, fmaf(a.z, w2, fmaf(a.w, w3, xrv))));
    float v = xlv + ef;
    v = fmaxf(v, 0.2f * v);                  // LeakyReLU(0.2): max(v, 0.2v), slope<1
    return red16(v * av2);                   // per-head logit, log2 domain
}

// Fused GATv2 logits + segment-softmax + aggregation, node-parallel.
// 64 threads (1 wave) per node, 4 nodes per 256-block.
__global__ void k_gat_agg(const int* __restrict__ rowptr,
                          const int* __restrict__ csr_src,
                          const float4* __restrict__ csr_ea,
                          const float* __restrict__ xl,   // [N,64]
                          const float* __restrict__ xr,   // [N,64]
                          const float* __restrict__ We,   // [4,64]
                          const float* __restrict__ att,  // [64]
                          const float* __restrict__ bias, // [64]
                          float* __restrict__ out,        // [N,64]
                          int N, int elu) {
    int t = threadIdx.x & 63;
    int n = blockIdx.x * 4 + (threadIdx.x >> 6);
    if (n >= N) return;
    float w0 = We[t], w1 = We[64 + t], w2 = We[128 + t], w3 = We[192 + t];
    float av2 = att[t] * 1.44269504088896f;   // log2(e)
    float xrv = xr[(size_t)n * 64 + t];
    const float* xl_t = xl + t;
    int beg = rowptr[n], end = rowptr[n + 1];

    float val;
    if (beg == end) {
        val = 0.f;
    } else {
        float xlv0;
        float m = edge_logit(csr_src[beg], csr_ea[beg], xrv, w0, w1, w2, w3, av2, xl_t, xlv0);
        float denom = 1.f, acc = xlv0;
        int j = beg + 1;
        for (; j + 1 < end; j += 2) {
            int s0 = csr_src[j], s1 = csr_src[j + 1];
            float4 a0 = csr_ea[j], a1 = csr_ea[j + 1];
            float x0, x1;
            float p0 = edge_logit(s0, a0, xrv, w0, w1, w2, w3, av2, xl_t, x0);
            float p1 = edge_logit(s1, a1, xrv, w0, w1, w2, w3, av2, xl_t, x1);
            if (__any(fmaxf(p0, p1) - m > 8.f)) {
                float mn = fmaxf(m, fmaxf(p0, p1));
                float sc = fexp2(m - mn);
                float e0 = fexp2(p0 - mn), e1 = fexp2(p1 - mn);
                denom = denom * sc + e0 + e1;
                acc = fmaf(acc, sc, fmaf(e0, x0, e1 * x1));
                m = mn;
            } else {
                float e0 = fexp2(p0 - m), e1 = fexp2(p1 - m);
                denom += e0 + e1;
                acc = fmaf(e0, x0, fmaf(e1, x1, acc));
            }
        }
        if (j < end) {
            float x0;
            float p0 = edge_logit(csr_src[j], csr_ea[j], xrv, w0, w1, w2, w3, av2, xl_t, x0);
            if (__any(p0 - m > 8.f)) {
                float mn = fmaxf(m, p0);
                float sc = fexp2(m - mn);
                float e0 = fexp2(p0 - mn);
                denom = denom * sc + e0;
                acc = fmaf(acc, sc, e0 * x0);
                m = mn;
            } else {
                float e0 = fexp2(p0 - m);
                denom += e0;
                acc = fmaf(e0, x0, acc);
            }
        }
        val = acc / denom;
    }
    val += bias[t];
    if (elu) val = (val > 0.f) ? val : expm1f(val);
    out[(size_t)n * 64 + t] = val;
}

// Run-length accumulating pool.
__global__ void k_pool(const float* __restrict__ y2,
                       const int* __restrict__ batch,
                       float* __restrict__ pool, float* __restrict__ cnt, int N) {
    const int CH = 256;
    int f = threadIdx.x & 63;
    int lane = threadIdx.x >> 6;
    int base = blockIdx.x * CH;
    int curg = -1;
    float acc = 0.f;
    float c = 0.f;
    for (int n = base + lane; n < base + CH && n < N; n += 4) {
        int g = batch[n];
        if (g != curg) {
            if (curg >= 0) {
                atomicAdd(pool + (size_t)curg * 64 + f, acc);
                if (f == 0) atomicAdd(cnt + curg, c);
            }
            curg = g; acc = 0.f; c = 0.f;
        }
        acc += y2[(size_t)n * 64 + f];
        c += 1.f;
    }
    if (curg >= 0) {
        atomicAdd(pool + (size_t)curg * 64 + f, acc);
        if (f == 0) atomicAdd(cnt + curg, c);
    }
}

// One block (64 threads) per graph: mean, 3 MLP heads.
__global__ void k_head(const float* __restrict__ pool, const float* __restrict__ cnt,
                       const float* __restrict__ Wg1, const float* __restrict__ bg1,
                       const float* __restrict__ Wg2, const float* __restrict__ bg2,
                       const float* __restrict__ Wp, const float* __restrict__ bp,
                       const float* __restrict__ Wc1, const float* __restrict__ bc1,
                       const float* __restrict__ Wc2, const float* __restrict__ bc2,
                       float* __restrict__ out) {
    int g = blockIdx.x, f = threadIdx.x;
    __shared__ float sg[64];
    __shared__ float sh[64];
    float inv = 1.f / fmaxf(cnt[g], 1.f);
    sg[f] = pool[(size_t)g * 64 + f] * inv;
    __syncthreads();
    float acc = bg1[f];
    for (int k = 0; k < 64; ++k) acc += sg[k] * Wg1[k * 64 + f];
    sh[f] = fmaxf(acc, 0.f);
    __syncthreads();
    if (f < 15) {
        float o = bg2[f];
        for (int k = 0; k < 64; ++k) o += sh[k] * Wg2[k * 15 + f];
        out[(size_t)g * 15 + f] = o;
    }
    if (f < 10) {
        float o = bp[f];
        for (int k = 0; k < 64; ++k) o += sg[k] * Wp[k * 10 + f];
        out[960 + (size_t)g * 10 + f] = o;
    }
    __syncthreads();
    float acc2 = bc1[f];
    for (int k = 0; k < 64; ++k) acc2 += sg[k] * Wc1[k * 64 + f];
    sh[f] = fmaxf(acc2, 0.f);
    __syncthreads();
    if (f == 0) {
        float v = bc2[0];
        for (int k = 0; k < 64; ++k) v += sh[k] * Wc2[k];
        out[1600 + g] = v;
    }
}

extern "C" void kernel_launch(void* const* d_in, const int* in_sizes, int n_in,
                              void* d_out, int out_size, void* d_ws, size_t ws_size,
                              hipStream_t stream) {
    const float* x     = (const float*)d_in[0];
    const int*   ei    = (const int*)d_in[1];
    const float* ea    = (const float*)d_in[2];
    const int*   batch = (const int*)d_in[3];
    const float* Wl1 = (const float*)d_in[4];
    const float* Wr1 = (const float*)d_in[5];
    const float* We1 = (const float*)d_in[6];
    const float* att1 = (const float*)d_in[7];
    const float* b1  = (const float*)d_in[8];
    const float* Wl2 = (const float*)d_in[9];
    const float* Wr2 = (const float*)d_in[10];
    const float* We2 = (const float*)d_in[11];
    const float* att2 = (const float*)d_in[12];
    const float* b2  = (const float*)d_in[13];
    const float* Wg1 = (const float*)d_in[14];
    const float* bg1 = (const float*)d_in[15];
    const float* Wg2 = (const float*)d_in[16];
    const float* bg2 = (const float*)d_in[17];
    const float* Wp  = (const float*)d_in[18];
    const float* bp  = (const float*)d_in[19];
    const float* Wc1 = (const float*)d_in[20];
    const float* bc1 = (const float*)d_in[21];
    const float* Wc2 = (const float*)d_in[22];
    const float* bc2 = (const float*)d_in[23];

    const int N = in_sizes[0] / 16;       // 100000
    const int E = in_sizes[2] / 4;        // 1600000
    const int* src = ei;
    const int* dst = ei + E;

    // workspace layout (floats)
    float* ws = (float*)d_ws;
    size_t NF = (size_t)N * 64;
    float* A  = ws;                       // xl1, later xr2
    float* B  = A + NF;                   // xr1, later xl2
    float* C  = B + NF;                   // y1, later y2
    float4* csr_ea = (float4*)(C + NF);   // [E] permuted edge_attr
    int* csr_src = (int*)(csr_ea + E);    // [E]
    int* rowptr  = csr_src + E;           // N+1
    int* deg     = rowptr + (N + 1);      // N (reused as fill)
    int* spart   = deg + N;               // N
    int* bsum    = spart + N;             // 128
    float* PL    = (float*)(bsum + 128);  // [64,64]
    float* CT    = PL + 64 * 64;          // [64]

    dim3 blk(256);
    int gE  = (E + 255) / 256;
    int gN  = (N + 255) / 256;
    int nb1 = (N + 1023) / 1024;
    int gAgg = (N + 3) / 4;
    int gLin = (N + 63) / 64;

    // ---- CSR build (shared by both layers) ----
    hipMemsetAsync(deg, 0, (size_t)N * sizeof(int), stream);
    k_deg<<<gE, blk, 0, stream>>>(dst, deg, E);
    k_scan1<<<nb1, blk, 0, stream>>>(deg, spart, bsum, N);
    k_scan2<<<1, 128, 0, stream>>>(bsum, nb1);
    k_scan3<<<gN, blk, 0, stream>>>(spart, bsum, rowptr, N);
    hipMemsetAsync(deg, 0, (size_t)N * sizeof(int), stream);  // reuse as fill
    k_scatter<<<gE, blk, 0, stream>>>(src, dst, (const float4*)ea, rowptr, deg,
                                      csr_src, csr_ea, E);

    // ---- Layer 1 ----
    k_lin_tiled<16><<<gLin, blk, 0, stream>>>(x, Wl1, Wr1, A, B, N);
    k_gat_agg<<<gAgg, blk, 0, stream>>>(rowptr, csr_src, csr_ea, A, B, We1, att1,
                                        b1, C, N, 1);

    // ---- Layer 2 ---- (xl2 -> B, xr2 -> A)
    k_lin_tiled<64><<<gLin, blk, 0, stream>>>(C, Wl2, Wr2, B, A, N);
    k_gat_agg<<<gAgg, blk, 0, stream>>>(rowptr, csr_src, csr_ea, B, A, We2, att2,
                                        b2, C, N, 0);

    // ---- Pool + heads ----
    hipMemsetAsync(PL, 0, (64 * 64 + 64) * sizeof(float), stream);
    k_pool<<<(N + 255) / 256, blk, 0, stream>>>(C, batch, PL, CT, N);
    k_head<<<64, 64, 0, stream>>>(PL, CT, Wg1, bg1, Wg2, bg2, Wp, bp,
                                  Wc1, bc1, Wc2, bc2, (float*)d_out);
}

// Round 9
// 473.126 us; speedup vs baseline: 1.2311x; 1.1994x over previous
//
#include <hip/hip_runtime.h>

#define DEVINL __device__ __forceinline__

#if __has_builtin(__builtin_amdgcn_exp2f)
DEVINL float fexp2(float x) { return __builtin_amdgcn_exp2f(x); }
#else
DEVINL float fexp2(float x) { return exp2f(x); }
#endif

// Sum over the 4 channel-quad lanes of a head (lane^1, lane^2) via ds_swizzle
// XOR immediates (BitMode: offset = (xor<<10) | 0x1F). Stays within 16-group.
DEVINL float red4(float pv) {
    pv += __int_as_float(__builtin_amdgcn_ds_swizzle(__float_as_int(pv), 0x041F));
    pv += __int_as_float(__builtin_amdgcn_ds_swizzle(__float_as_int(pv), 0x081F));
    return pv;
}

// LDS-tiled GEMM: out[n, 0:128] = x[n, 0:K] @ [Wa | Wb].
template <int K>
__global__ void k_lin_tiled(const float* __restrict__ x,
                            const float* __restrict__ Wa,
                            const float* __restrict__ Wb,
                            float* __restrict__ oa, float* __restrict__ ob,
                            int N) {
    __shared__ float sx[64 * K];
    __shared__ float sw[K * 128];
    int t = threadIdx.x;
    int base = blockIdx.x * 64;

    const int WTOT = K * 64 / 4;
    for (int i = t; i < WTOT; i += 256) {
        float4 wa = ((const float4*)Wa)[i];
        float4 wb = ((const float4*)Wb)[i];
        int k = (i * 4) >> 6, f = (i * 4) & 63;
        *(float4*)&sw[k * 128 + f] = wa;
        *(float4*)&sw[k * 128 + 64 + f] = wb;
    }
    const int XTOT = 64 * K / 4;
    for (int i = t; i < XTOT; i += 256) {
        int n = (i * 4) / K, kk = (i * 4) % K;
        float4 v = make_float4(0.f, 0.f, 0.f, 0.f);
        if (base + n < N) v = *(const float4*)&x[(size_t)(base + n) * K + kk];
        *(float4*)&sx[n * K + kk] = v;
    }
    __syncthreads();

    int fq = t & 31;
    int nq = t >> 5;
    float acc[8][4];
#pragma unroll
    for (int i = 0; i < 8; ++i)
#pragma unroll
        for (int c = 0; c < 4; ++c) acc[i][c] = 0.f;

    for (int k0 = 0; k0 < K; k0 += 4) {
        float4 xv[8];
#pragma unroll
        for (int i = 0; i < 8; ++i)
            xv[i] = *(const float4*)&sx[(nq * 8 + i) * K + k0];
#pragma unroll
        for (int kk = 0; kk < 4; ++kk) {
            float4 w = *(const float4*)&sw[(k0 + kk) * 128 + fq * 4];
#pragma unroll
            for (int i = 0; i < 8; ++i) {
                float xs = (kk == 0) ? xv[i].x : (kk == 1) ? xv[i].y
                         : (kk == 2) ? xv[i].z : xv[i].w;
                acc[i][0] = fmaf(xs, w.x, acc[i][0]);
                acc[i][1] = fmaf(xs, w.y, acc[i][1]);
                acc[i][2] = fmaf(xs, w.z, acc[i][2]);
                acc[i][3] = fmaf(xs, w.w, acc[i][3]);
            }
        }
    }

    int col = fq * 4;
    float* o = (col < 64) ? oa : ob;
    int c = col & 63;
#pragma unroll
    for (int i = 0; i < 8; ++i) {
        int n = base + nq * 8 + i;
        if (n < N)
            *(float4*)&o[(size_t)n * 64 + c] =
                make_float4(acc[i][0], acc[i][1], acc[i][2], acc[i][3]);
    }
}

// ---- CSR build ----
__global__ void k_deg(const int* __restrict__ dst, int* __restrict__ deg, int E) {
    int e = blockIdx.x * blockDim.x + threadIdx.x;
    if (e < E) atomicAdd(&deg[dst[e]], 1);
}

__global__ void k_scan1(const int* __restrict__ deg, int* __restrict__ spart,
                        int* __restrict__ bsum, int N) {
    __shared__ int sh[256];
    int base = blockIdx.x * 1024;
    int t = threadIdx.x;
    int v[4]; int sum = 0;
#pragma unroll
    for (int i = 0; i < 4; ++i) {
        int idx = base + t * 4 + i;
        v[i] = (idx < N) ? deg[idx] : 0;
        sum += v[i];
    }
    sh[t] = sum;
    __syncthreads();
    for (int off = 1; off < 256; off <<= 1) {
        int x = (t >= off) ? sh[t - off] : 0;
        __syncthreads();
        sh[t] += x;
        __syncthreads();
    }
    int run = (t > 0) ? sh[t - 1] : 0;
#pragma unroll
    for (int i = 0; i < 4; ++i) {
        run += v[i];
        int idx = base + t * 4 + i;
        if (idx < N) spart[idx] = run;
    }
    if (t == 255) bsum[blockIdx.x] = sh[255];
}

__global__ void k_scan2(int* __restrict__ bsum, int nb) {
    __shared__ int sh[128];
    int t = threadIdx.x;
    sh[t] = (t < nb) ? bsum[t] : 0;
    __syncthreads();
    for (int off = 1; off < 128; off <<= 1) {
        int x = (t >= off) ? sh[t - off] : 0;
        __syncthreads();
        sh[t] += x;
        __syncthreads();
    }
    if (t < nb) bsum[t] = (t > 0) ? sh[t - 1] : 0;
}

__global__ void k_scan3(const int* __restrict__ spart, const int* __restrict__ bsum,
                        int* __restrict__ rowptr, int N) {
    int i = blockIdx.x * blockDim.x + threadIdx.x;
    if (i < N) rowptr[i + 1] = spart[i] + bsum[i >> 10];
    if (i == 0) rowptr[0] = 0;
}

__global__ void k_scatter(const int* __restrict__ src, const int* __restrict__ dst,
                          const float4* __restrict__ ea,
                          const int* __restrict__ rowptr, int* __restrict__ fill,
                          int* __restrict__ csr_src, float4* __restrict__ csr_ea, int E) {
    int e = blockIdx.x * blockDim.x + threadIdx.x;
    if (e >= E) return;
    int d = dst[e];
    int pos = rowptr[d] + atomicAdd(&fill[d], 1);
    csr_src[pos] = src[e];
    csr_ea[pos] = ea[e];
}

// Fused GATv2 logits + segment-softmax + aggregation, node-parallel,
// EDGE-QUAD layout: wave = 1 node; lane l: group g=l>>4 owns edge slot jb+g,
// lane q=l&15 owns channels 4q..4q+3 (head q>>2) as float4.
// Branchless always-rescale online softmax (log2 domain); per-node merge of
// the 4 group states via shfl_xor(16/32).
__global__ void k_gat_agg(const int* __restrict__ rowptr,
                          const int* __restrict__ csr_src,
                          const float4* __restrict__ csr_ea,
                          const float* __restrict__ xl,   // [N,64]
                          const float* __restrict__ xr,   // [N,64]
                          const float* __restrict__ We,   // [4,64]
                          const float* __restrict__ att,  // [64]
                          const float* __restrict__ bias, // [64]
                          float* __restrict__ out,        // [N,64]
                          int N, int elu) {
    int l = threadIdx.x & 63;
    int n = blockIdx.x * 4 + (threadIdx.x >> 6);
    if (n >= N) return;
    int q = l & 15;
    int g = l >> 4;
    int f4 = q * 4;
    const float LOG2E = 1.44269504088896f;

    float4 w0 = *(const float4*)&We[f4];
    float4 w1 = *(const float4*)&We[64 + f4];
    float4 w2 = *(const float4*)&We[128 + f4];
    float4 w3 = *(const float4*)&We[192 + f4];
    float4 at = *(const float4*)&att[f4];
    at.x *= LOG2E; at.y *= LOG2E; at.z *= LOG2E; at.w *= LOG2E;
    float4 xr4 = *(const float4*)&xr[(size_t)n * 64 + f4];

    int beg = rowptr[n], end = rowptr[n + 1];
    const float4* xl4 = (const float4*)xl;

    float m = -1e30f, den = 0.f;
    float4 acc = make_float4(0.f, 0.f, 0.f, 0.f);

    for (int jb = beg; jb < end; jb += 4) {
        int j = jb + g;
        bool valid = (j < end);
        int jj = valid ? j : end - 1;
        int s = csr_src[jj];
        float4 a = csr_ea[jj];
        float4 xv = xl4[(unsigned)s * 16u + (unsigned)q];
        // v = xl + xr + ef (ef chain seeded with xr)
        float vx = fmaf(a.x, w0.x, fmaf(a.y, w1.x, fmaf(a.z, w2.x, fmaf(a.w, w3.x, xr4.x)))) + xv.x;
        float vy = fmaf(a.x, w0.y, fmaf(a.y, w1.y, fmaf(a.z, w2.y, fmaf(a.w, w3.y, xr4.y)))) + xv.y;
        float vz = fmaf(a.x, w0.z, fmaf(a.y, w1.z, fmaf(a.z, w2.z, fmaf(a.w, w3.z, xr4.z)))) + xv.z;
        float vw = fmaf(a.x, w0.w, fmaf(a.y, w1.w, fmaf(a.z, w2.w, fmaf(a.w, w3.w, xr4.w)))) + xv.w;
        // LeakyReLU(0.2) = max(v, 0.2v)
        vx = fmaxf(vx, 0.2f * vx);
        vy = fmaxf(vy, 0.2f * vy);
        vz = fmaxf(vz, 0.2f * vz);
        vw = fmaxf(vw, 0.2f * vw);
        // quad-partial of att-dot (log2 domain), then 2-step swizzle reduce
        float pv = fmaf(vx, at.x, fmaf(vy, at.y, fmaf(vz, at.z, vw * at.w)));
        pv = red4(pv);
        pv = valid ? pv : -3.0e38f;   // invalid -> e == 0 exactly
        // branchless online softmax update
        float mn = fmaxf(m, pv);
        float sc = fexp2(m - mn);     // first valid edge: exp2(-1e30)=0
        float e  = fexp2(pv - mn);
        den = fmaf(den, sc, e);
        acc.x = fmaf(e, xv.x, acc.x * sc);
        acc.y = fmaf(e, xv.y, acc.y * sc);
        acc.z = fmaf(e, xv.z, acc.z * sc);
        acc.w = fmaf(e, xv.w, acc.w * sc);
        m = mn;
    }

    // merge the 4 group states (flash-style), lanes l^16 then l^32
#pragma unroll
    for (int mask = 16; mask <= 32; mask <<= 1) {
        float m2 = __shfl_xor(m, mask);
        float d2 = __shfl_xor(den, mask);
        float ax = __shfl_xor(acc.x, mask);
        float ay = __shfl_xor(acc.y, mask);
        float az = __shfl_xor(acc.z, mask);
        float aw = __shfl_xor(acc.w, mask);
        float mn = fmaxf(m, m2);
        float s1 = fexp2(m - mn);
        float s2 = fexp2(m2 - mn);
        den = den * s1 + d2 * s2;
        acc.x = acc.x * s1 + ax * s2;
        acc.y = acc.y * s1 + ay * s2;
        acc.z = acc.z * s1 + az * s2;
        acc.w = acc.w * s1 + aw * s2;
        m = mn;
    }

    float inv = (den > 0.f) ? 1.f / den : 0.f;
    float4 b4 = *(const float4*)&bias[f4];
    float4 val;
    val.x = fmaf(acc.x, inv, b4.x);
    val.y = fmaf(acc.y, inv, b4.y);
    val.z = fmaf(acc.z, inv, b4.z);
    val.w = fmaf(acc.w, inv, b4.w);
    if (elu) {
        val.x = (val.x > 0.f) ? val.x : expm1f(val.x);
        val.y = (val.y > 0.f) ? val.y : expm1f(val.y);
        val.z = (val.z > 0.f) ? val.z : expm1f(val.z);
        val.w = (val.w > 0.f) ? val.w : expm1f(val.w);
    }
    if (l < 16) ((float4*)out)[(size_t)n * 16 + q] = val;
}

// Run-length accumulating pool.
__global__ void k_pool(const float* __restrict__ y2,
                       const int* __restrict__ batch,
                       float* __restrict__ pool, float* __restrict__ cnt, int N) {
    const int CH = 256;
    int f = threadIdx.x & 63;
    int lane = threadIdx.x >> 6;
    int base = blockIdx.x * CH;
    int curg = -1;
    float acc = 0.f;
    float c = 0.f;
    for (int n = base + lane; n < base + CH && n < N; n += 4) {
        int g = batch[n];
        if (g != curg) {
            if (curg >= 0) {
                atomicAdd(pool + (size_t)curg * 64 + f, acc);
                if (f == 0) atomicAdd(cnt + curg, c);
            }
            curg = g; acc = 0.f; c = 0.f;
        }
        acc += y2[(size_t)n * 64 + f];
        c += 1.f;
    }
    if (curg >= 0) {
        atomicAdd(pool + (size_t)curg * 64 + f, acc);
        if (f == 0) atomicAdd(cnt + curg, c);
    }
}

// One block (64 threads) per graph: mean, 3 MLP heads.
__global__ void k_head(const float* __restrict__ pool, const float* __restrict__ cnt,
                       const float* __restrict__ Wg1, const float* __restrict__ bg1,
                       const float* __restrict__ Wg2, const float* __restrict__ bg2,
                       const float* __restrict__ Wp, const float* __restrict__ bp,
                       const float* __restrict__ Wc1, const float* __restrict__ bc1,
                       const float* __restrict__ Wc2, const float* __restrict__ bc2,
                       float* __restrict__ out) {
    int g = blockIdx.x, f = threadIdx.x;
    __shared__ float sg[64];
    __shared__ float sh[64];
    float inv = 1.f / fmaxf(cnt[g], 1.f);
    sg[f] = pool[(size_t)g * 64 + f] * inv;
    __syncthreads();
    float acc = bg1[f];
    for (int k = 0; k < 64; ++k) acc += sg[k] * Wg1[k * 64 + f];
    sh[f] = fmaxf(acc, 0.f);
    __syncthreads();
    if (f < 15) {
        float o = bg2[f];
        for (int k = 0; k < 64; ++k) o += sh[k] * Wg2[k * 15 + f];
        out[(size_t)g * 15 + f] = o;
    }
    if (f < 10) {
        float o = bp[f];
        for (int k = 0; k < 64; ++k) o += sg[k] * Wp[k * 10 + f];
        out[960 + (size_t)g * 10 + f] = o;
    }
    __syncthreads();
    float acc2 = bc1[f];
    for (int k = 0; k < 64; ++k) acc2 += sg[k] * Wc1[k * 64 + f];
    sh[f] = fmaxf(acc2, 0.f);
    __syncthreads();
    if (f == 0) {
        float v = bc2[0];
        for (int k = 0; k < 64; ++k) v += sh[k] * Wc2[k];
        out[1600 + g] = v;
    }
}

extern "C" void kernel_launch(void* const* d_in, const int* in_sizes, int n_in,
                              void* d_out, int out_size, void* d_ws, size_t ws_size,
                              hipStream_t stream) {
    const float* x     = (const float*)d_in[0];
    const int*   ei    = (const int*)d_in[1];
    const float* ea    = (const float*)d_in[2];
    const int*   batch = (const int*)d_in[3];
    const float* Wl1 = (const float*)d_in[4];
    const float* Wr1 = (const float*)d_in[5];
    const float* We1 = (const float*)d_in[6];
    const float* att1 = (const float*)d_in[7];
    const float* b1  = (const float*)d_in[8];
    const float* Wl2 = (const float*)d_in[9];
    const float* Wr2 = (const float*)d_in[10];
    const float* We2 = (const float*)d_in[11];
    const float* att2 = (const float*)d_in[12];
    const float* b2  = (const float*)d_in[13];
    const float* Wg1 = (const float*)d_in[14];
    const float* bg1 = (const float*)d_in[15];
    const float* Wg2 = (const float*)d_in[16];
    const float* bg2 = (const float*)d_in[17];
    const float* Wp  = (const float*)d_in[18];
    const float* bp  = (const float*)d_in[19];
    const float* Wc1 = (const float*)d_in[20];
    const float* bc1 = (const float*)d_in[21];
    const float* Wc2 = (const float*)d_in[22];
    const float* bc2 = (const float*)d_in[23];

    const int N = in_sizes[0] / 16;       // 100000
    const int E = in_sizes[2] / 4;        // 1600000
    const int* src = ei;
    const int* dst = ei + E;

    // workspace layout (floats)
    float* ws = (float*)d_ws;
    size_t NF = (size_t)N * 64;
    float* A  = ws;                       // xl1, later xr2
    float* B  = A + NF;                   // xr1, later xl2
    float* C  = B + NF;                   // y1, later y2
    float4* csr_ea = (float4*)(C + NF);   // [E] permuted edge_attr
    int* csr_src = (int*)(csr_ea + E);    // [E]
    int* rowptr  = csr_src + E;           // N+1
    int* deg     = rowptr + (N + 1);      // N (reused as fill)
    int* spart   = deg + N;               // N
    int* bsum    = spart + N;             // 128
    float* PL    = (float*)(bsum + 128);  // [64,64]
    float* CT    = PL + 64 * 64;          // [64]

    dim3 blk(256);
    int gE  = (E + 255) / 256;
    int gN  = (N + 255) / 256;
    int nb1 = (N + 1023) / 1024;
    int gAgg = (N + 3) / 4;
    int gLin = (N + 63) / 64;

    // ---- CSR build (shared by both layers) ----
    hipMemsetAsync(deg, 0, (size_t)N * sizeof(int), stream);
    k_deg<<<gE, blk, 0, stream>>>(dst, deg, E);
    k_scan1<<<nb1, blk, 0, stream>>>(deg, spart, bsum, N);
    k_scan2<<<1, 128, 0, stream>>>(bsum, nb1);
    k_scan3<<<gN, blk, 0, stream>>>(spart, bsum, rowptr, N);
    hipMemsetAsync(deg, 0, (size_t)N * sizeof(int), stream);  // reuse as fill
    k_scatter<<<gE, blk, 0, stream>>>(src, dst, (const float4*)ea, rowptr, deg,
                                      csr_src, csr_ea, E);

    // ---- Layer 1 ----
    k_lin_tiled<16><<<gLin, blk, 0, stream>>>(x, Wl1, Wr1, A, B, N);
    k_gat_agg<<<gAgg, blk, 0, stream>>>(rowptr, csr_src, csr_ea, A, B, We1, att1,
                                        b1, C, N, 1);

    // ---- Layer 2 ---- (xl2 -> B, xr2 -> A)
    k_lin_tiled<64><<<gLin, blk, 0, stream>>>(C, Wl2, Wr2, B, A, N);
    k_gat_agg<<<gAgg, blk, 0, stream>>>(rowptr, csr_src, csr_ea, B, A, We2, att2,
                                        b2, C, N, 0);

    // ---- Pool + heads ----
    hipMemsetAsync(PL, 0, (64 * 64 + 64) * sizeof(float), stream);
    k_pool<<<(N + 255) / 256, blk, 0, stream>>>(C, batch, PL, CT, N);
    k_head<<<64, 64, 0, stream>>>(PL, CT, Wg1, bg1, Wg2, bg2, Wp, bp,
                                  Wc1, bc1, Wc2, bc2, (float*)d_out);
}

// Round 11
// 462.034 us; speedup vs baseline: 1.2607x; 1.0240x over previous
//
#include <hip/hip_runtime.h>

#define DEVINL __device__ __forceinline__

#if __has_builtin(__builtin_amdgcn_exp2f)
DEVINL float fexp2(float x) { return __builtin_amdgcn_exp2f(x); }
#else
DEVINL float fexp2(float x) { return exp2f(x); }
#endif

// Sum over the 4 channel-quad lanes of a head (lane^1, lane^2) via ds_swizzle
// XOR immediates (BitMode: offset = (xor<<10) | 0x1F).
DEVINL float red4(float pv) {
    pv += __int_as_float(__builtin_amdgcn_ds_swizzle(__float_as_int(pv), 0x041F));
    pv += __int_as_float(__builtin_amdgcn_ds_swizzle(__float_as_int(pv), 0x081F));
    return pv;
}

// LDS-tiled GEMM: out[n, 0:128] = x[n, 0:K] @ [Wa | Wb].
template <int K>
__global__ void k_lin_tiled(const float* __restrict__ x,
                            const float* __restrict__ Wa,
                            const float* __restrict__ Wb,
                            float* __restrict__ oa, float* __restrict__ ob,
                            int N) {
    __shared__ float sx[64 * K];
    __shared__ float sw[K * 128];
    int t = threadIdx.x;
    int base = blockIdx.x * 64;

    const int WTOT = K * 64 / 4;
    for (int i = t; i < WTOT; i += 256) {
        float4 wa = ((const float4*)Wa)[i];
        float4 wb = ((const float4*)Wb)[i];
        int k = (i * 4) >> 6, f = (i * 4) & 63;
        *(float4*)&sw[k * 128 + f] = wa;
        *(float4*)&sw[k * 128 + 64 + f] = wb;
    }
    const int XTOT = 64 * K / 4;
    for (int i = t; i < XTOT; i += 256) {
        int n = (i * 4) / K, kk = (i * 4) % K;
        float4 v = make_float4(0.f, 0.f, 0.f, 0.f);
        if (base + n < N) v = *(const float4*)&x[(size_t)(base + n) * K + kk];
        *(float4*)&sx[n * K + kk] = v;
    }
    __syncthreads();

    int fq = t & 31;
    int nq = t >> 5;
    float acc[8][4];
#pragma unroll
    for (int i = 0; i < 8; ++i)
#pragma unroll
        for (int c = 0; c < 4; ++c) acc[i][c] = 0.f;

    for (int k0 = 0; k0 < K; k0 += 4) {
        float4 xv[8];
#pragma unroll
        for (int i = 0; i < 8; ++i)
            xv[i] = *(const float4*)&sx[(nq * 8 + i) * K + k0];
#pragma unroll
        for (int kk = 0; kk < 4; ++kk) {
            float4 w = *(const float4*)&sw[(k0 + kk) * 128 + fq * 4];
#pragma unroll
            for (int i = 0; i < 8; ++i) {
                float xs = (kk == 0) ? xv[i].x : (kk == 1) ? xv[i].y
                         : (kk == 2) ? xv[i].z : xv[i].w;
                acc[i][0] = fmaf(xs, w.x, acc[i][0]);
                acc[i][1] = fmaf(xs, w.y, acc[i][1]);
                acc[i][2] = fmaf(xs, w.z, acc[i][2]);
                acc[i][3] = fmaf(xs, w.w, acc[i][3]);
            }
        }
    }

    int col = fq * 4;
    float* o = (col < 64) ? oa : ob;
    int c = col & 63;
#pragma unroll
    for (int i = 0; i < 8; ++i) {
        int n = base + nq * 8 + i;
        if (n < N)
            *(float4*)&o[(size_t)n * 64 + c] =
                make_float4(acc[i][0], acc[i][1], acc[i][2], acc[i][3]);
    }
}

// ---- CSR build ----
__global__ void k_deg(const int* __restrict__ dst, int* __restrict__ deg, int E) {
    int e = blockIdx.x * blockDim.x + threadIdx.x;
    if (e < E) atomicAdd(&deg[dst[e]], 1);
}

__global__ void k_scan1(const int* __restrict__ deg, int* __restrict__ spart,
                        int* __restrict__ bsum, int N) {
    __shared__ int sh[256];
    int base = blockIdx.x * 1024;
    int t = threadIdx.x;
    int v[4]; int sum = 0;
#pragma unroll
    for (int i = 0; i < 4; ++i) {
        int idx = base + t * 4 + i;
        v[i] = (idx < N) ? deg[idx] : 0;
        sum += v[i];
    }
    sh[t] = sum;
    __syncthreads();
    for (int off = 1; off < 256; off <<= 1) {
        int x = (t >= off) ? sh[t - off] : 0;
        __syncthreads();
        sh[t] += x;
        __syncthreads();
    }
    int run = (t > 0) ? sh[t - 1] : 0;
#pragma unroll
    for (int i = 0; i < 4; ++i) {
        run += v[i];
        int idx = base + t * 4 + i;
        if (idx < N) spart[idx] = run;
    }
    if (t == 255) bsum[blockIdx.x] = sh[255];
}

__global__ void k_scan2(int* __restrict__ bsum, int nb) {
    __shared__ int sh[128];
    int t = threadIdx.x;
    sh[t] = (t < nb) ? bsum[t] : 0;
    __syncthreads();
    for (int off = 1; off < 128; off <<= 1) {
        int x = (t >= off) ? sh[t - off] : 0;
        __syncthreads();
        sh[t] += x;
        __syncthreads();
    }
    if (t < nb) bsum[t] = (t > 0) ? sh[t - 1] : 0;
}

__global__ void k_scan3(const int* __restrict__ spart, const int* __restrict__ bsum,
                        int* __restrict__ rowptr, int N) {
    int i = blockIdx.x * blockDim.x + threadIdx.x;
    if (i < N) rowptr[i + 1] = spart[i] + bsum[i >> 10];
    if (i == 0) rowptr[0] = 0;
}

// Scatter edges into CSR order.
// PACKED: one 32B record {ea(16) | src(4) | pad} per slot -> both stores hit
// the SAME 64B line (halves random-line RMW traffic vs split arrays).
template <bool PACKED>
__global__ void k_scatter(const int* __restrict__ src, const int* __restrict__ dst,
                          const float4* __restrict__ ea,
                          const int* __restrict__ rowptr, int* __restrict__ fill,
                          float4* __restrict__ rec, int* __restrict__ csr_src, int E) {
    int e = blockIdx.x * blockDim.x + threadIdx.x;
    if (e >= E) return;
    int d = dst[e];
    float4 a = ea[e];
    int s = src[e];
    int pos = rowptr[d] + atomicAdd(&fill[d], 1);
    if (PACKED) {
        rec[(size_t)pos * 2] = a;
        *(int*)(rec + (size_t)pos * 2 + 1) = s;
    } else {
        rec[pos] = a;
        csr_src[pos] = s;
    }
}

// Fused GATv2 logits + segment-softmax + aggregation, node-parallel,
// EDGE-QUAD layout: wave = 1 node; lane l: group g=l>>4 owns edge slot jb+g,
// lane q=l&15 owns channels 4q..4q+3 (head q>>2) as float4.
template <bool PACKED>
__global__ void k_gat_agg(const int* __restrict__ rowptr,
                          const float4* __restrict__ rec,   // packed recs or csr_ea
                          const int* __restrict__ csr_src,  // used when !PACKED
                          const float* __restrict__ xl,   // [N,64]
                          const float* __restrict__ xr,   // [N,64]
                          const float* __restrict__ We,   // [4,64]
                          const float* __restrict__ att,  // [64]
                          const float* __restrict__ bias, // [64]
                          float* __restrict__ out,        // [N,64]
                          int N, int elu) {
    int l = threadIdx.x & 63;
    int n = blockIdx.x * 4 + (threadIdx.x >> 6);
    if (n >= N) return;
    int q = l & 15;
    int g = l >> 4;
    int f4 = q * 4;
    const float LOG2E = 1.44269504088896f;

    float4 w0 = *(const float4*)&We[f4];
    float4 w1 = *(const float4*)&We[64 + f4];
    float4 w2 = *(const float4*)&We[128 + f4];
    float4 w3 = *(const float4*)&We[192 + f4];
    float4 at = *(const float4*)&att[f4];
    at.x *= LOG2E; at.y *= LOG2E; at.z *= LOG2E; at.w *= LOG2E;
    float4 xr4 = *(const float4*)&xr[(size_t)n * 64 + f4];

    int beg = rowptr[n], end = rowptr[n + 1];
    const float4* xl4 = (const float4*)xl;

    float m = -1e30f, den = 0.f;
    float4 acc = make_float4(0.f, 0.f, 0.f, 0.f);

    for (int jb = beg; jb < end; jb += 4) {
        int j = jb + g;
        bool valid = (j < end);
        int jj = valid ? j : end - 1;
        float4 a; int s;
        if (PACKED) {
            a = rec[(size_t)jj * 2];
            s = *(const int*)(rec + (size_t)jj * 2 + 1);
        } else {
            a = rec[jj];
            s = csr_src[jj];
        }
        float4 xv = xl4[(unsigned)s * 16u + (unsigned)q];
        float vx = fmaf(a.x, w0.x, fmaf(a.y, w1.x, fmaf(a.z, w2.x, fmaf(a.w, w3.x, xr4.x)))) + xv.x;
        float vy = fmaf(a.x, w0.y, fmaf(a.y, w1.y, fmaf(a.z, w2.y, fmaf(a.w, w3.y, xr4.y)))) + xv.y;
        float vz = fmaf(a.x, w0.z, fmaf(a.y, w1.z, fmaf(a.z, w2.z, fmaf(a.w, w3.z, xr4.z)))) + xv.z;
        float vw = fmaf(a.x, w0.w, fmaf(a.y, w1.w, fmaf(a.z, w2.w, fmaf(a.w, w3.w, xr4.w)))) + xv.w;
        vx = fmaxf(vx, 0.2f * vx);
        vy = fmaxf(vy, 0.2f * vy);
        vz = fmaxf(vz, 0.2f * vz);
        vw = fmaxf(vw, 0.2f * vw);
        float pv = fmaf(vx, at.x, fmaf(vy, at.y, fmaf(vz, at.z, vw * at.w)));
        pv = red4(pv);
        pv = valid ? pv : -3.0e38f;
        float mn = fmaxf(m, pv);
        float sc = fexp2(m - mn);
        float e  = fexp2(pv - mn);
        den = fmaf(den, sc, e);
        acc.x = fmaf(e, xv.x, acc.x * sc);
        acc.y = fmaf(e, xv.y, acc.y * sc);
        acc.z = fmaf(e, xv.z, acc.z * sc);
        acc.w = fmaf(e, xv.w, acc.w * sc);
        m = mn;
    }

#pragma unroll
    for (int mask = 16; mask <= 32; mask <<= 1) {
        float m2 = __shfl_xor(m, mask);
        float d2 = __shfl_xor(den, mask);
        float ax = __shfl_xor(acc.x, mask);
        float ay = __shfl_xor(acc.y, mask);
        float az = __shfl_xor(acc.z, mask);
        float aw = __shfl_xor(acc.w, mask);
        float mn = fmaxf(m, m2);
        float s1 = fexp2(m - mn);
        float s2 = fexp2(m2 - mn);
        den = den * s1 + d2 * s2;
        acc.x = acc.x * s1 + ax * s2;
        acc.y = acc.y * s1 + ay * s2;
        acc.z = acc.z * s1 + az * s2;
        acc.w = acc.w * s1 + aw * s2;
        m = mn;
    }

    float inv = (den > 0.f) ? 1.f / den : 0.f;
    float4 b4 = *(const float4*)&bias[f4];
    float4 val;
    val.x = fmaf(acc.x, inv, b4.x);
    val.y = fmaf(acc.y, inv, b4.y);
    val.z = fmaf(acc.z, inv, b4.z);
    val.w = fmaf(acc.w, inv, b4.w);
    if (elu) {
        val.x = (val.x > 0.f) ? val.x : expm1f(val.x);
        val.y = (val.y > 0.f) ? val.y : expm1f(val.y);
        val.z = (val.z > 0.f) ? val.z : expm1f(val.z);
        val.w = (val.w > 0.f) ? val.w : expm1f(val.w);
    }
    if (l < 16) ((float4*)out)[(size_t)n * 16 + q] = val;
}

// Run-length accumulating pool.
__global__ void k_pool(const float* __restrict__ y2,
                       const int* __restrict__ batch,
                       float* __restrict__ pool, float* __restrict__ cnt, int N) {
    const int CH = 256;
    int f = threadIdx.x & 63;
    int lane = threadIdx.x >> 6;
    int base = blockIdx.x * CH;
    int curg = -1;
    float acc = 0.f;
    float c = 0.f;
    for (int n = base + lane; n < base + CH && n < N; n += 4) {
        int g = batch[n];
        if (g != curg) {
            if (curg >= 0) {
                atomicAdd(pool + (size_t)curg * 64 + f, acc);
                if (f == 0) atomicAdd(cnt + curg, c);
            }
            curg = g; acc = 0.f; c = 0.f;
        }
        acc += y2[(size_t)n * 64 + f];
        c += 1.f;
    }
    if (curg >= 0) {
        atomicAdd(pool + (size_t)curg * 64 + f, acc);
        if (f == 0) atomicAdd(cnt + curg, c);
    }
}

// One block (64 threads) per graph: mean, 3 MLP heads.
__global__ void k_head(const float* __restrict__ pool, const float* __restrict__ cnt,
                       const float* __restrict__ Wg1, const float* __restrict__ bg1,
                       const float* __restrict__ Wg2, const float* __restrict__ bg2,
                       const float* __restrict__ Wp, const float* __restrict__ bp,
                       const float* __restrict__ Wc1, const float* __restrict__ bc1,
                       const float* __restrict__ Wc2, const float* __restrict__ bc2,
                       float* __restrict__ out) {
    int g = blockIdx.x, f = threadIdx.x;
    __shared__ float sg[64];
    __shared__ float sh[64];
    float inv = 1.f / fmaxf(cnt[g], 1.f);
    sg[f] = pool[(size_t)g * 64 + f] * inv;
    __syncthreads();
    float acc = bg1[f];
    for (int k = 0; k < 64; ++k) acc += sg[k] * Wg1[k * 64 + f];
    sh[f] = fmaxf(acc, 0.f);
    __syncthreads();
    if (f < 15) {
        float o = bg2[f];
        for (int k = 0; k < 64; ++k) o += sh[k] * Wg2[k * 15 + f];
        out[(size_t)g * 15 + f] = o;
    }
    if (f < 10) {
        float o = bp[f];
        for (int k = 0; k < 64; ++k) o += sg[k] * Wp[k * 10 + f];
        out[960 + (size_t)g * 10 + f] = o;
    }
    __syncthreads();
    float acc2 = bc1[f];
    for (int k = 0; k < 64; ++k) acc2 += sg[k] * Wc1[k * 64 + f];
    sh[f] = fmaxf(acc2, 0.f);
    __syncthreads();
    if (f == 0) {
        float v = bc2[0];
        for (int k = 0; k < 64; ++k) v += sh[k] * Wc2[k];
        out[1600 + g] = v;
    }
}

extern "C" void kernel_launch(void* const* d_in, const int* in_sizes, int n_in,
                              void* d_out, int out_size, void* d_ws, size_t ws_size,
                              hipStream_t stream) {
    const float* x     = (const float*)d_in[0];
    const int*   ei    = (const int*)d_in[1];
    const float* ea    = (const float*)d_in[2];
    const int*   batch = (const int*)d_in[3];
    const float* Wl1 = (const float*)d_in[4];
    const float* Wr1 = (const float*)d_in[5];
    const float* We1 = (const float*)d_in[6];
    const float* att1 = (const float*)d_in[7];
    const float* b1  = (const float*)d_in[8];
    const float* Wl2 = (const float*)d_in[9];
    const float* Wr2 = (const float*)d_in[10];
    const float* We2 = (const float*)d_in[11];
    const float* att2 = (const float*)d_in[12];
    const float* b2  = (const float*)d_in[13];
    const float* Wg1 = (const float*)d_in[14];
    const float* bg1 = (const float*)d_in[15];
    const float* Wg2 = (const float*)d_in[16];
    const float* bg2 = (const float*)d_in[17];
    const float* Wp  = (const float*)d_in[18];
    const float* bp  = (const float*)d_in[19];
    const float* Wc1 = (const float*)d_in[20];
    const float* bc1 = (const float*)d_in[21];
    const float* Wc2 = (const float*)d_in[22];
    const float* bc2 = (const float*)d_in[23];

    const int N = in_sizes[0] / 16;       // 100000
    const int E = in_sizes[2] / 4;        // 1600000
    const int* src = ei;
    const int* dst = ei + E;

    // workspace layout (bytes)
    size_t NF = (size_t)N * 64;
    size_t tail = ((size_t)(N + 1) + N + N + 128 + 4096 + 64) * 4;
    size_t need_packed = 3 * NF * 4 + (size_t)E * 32 + tail;
    bool packed = (ws_size >= need_packed);

    char* w = (char*)d_ws;
    float* A = (float*)w; w += NF * 4;
    float* B = (float*)w; w += NF * 4;
    float* C = (float*)w; w += NF * 4;
    float4* rec; int* csr_src;
    if (packed) {
        rec = (float4*)w; w += (size_t)E * 32; csr_src = nullptr;
    } else {
        rec = (float4*)w; w += (size_t)E * 16;
        csr_src = (int*)w; w += (size_t)E * 4;
    }
    int* rowptr = (int*)w; w += (size_t)(N + 1) * 4;
    int* deg    = (int*)w; w += (size_t)N * 4;      // reused as fill
    int* spart  = (int*)w; w += (size_t)N * 4;
    int* bsum   = (int*)w; w += 128 * 4;
    float* PL   = (float*)w; w += 4096 * 4;
    float* CT   = (float*)w;

    dim3 blk(256);
    int gE  = (E + 255) / 256;
    int gN  = (N + 255) / 256;
    int nb1 = (N + 1023) / 1024;
    int gAgg = (N + 3) / 4;
    int gLin = (N + 63) / 64;

    // ---- CSR build (shared by both layers) ----
    hipMemsetAsync(deg, 0, (size_t)N * sizeof(int), stream);
    k_deg<<<gE, blk, 0, stream>>>(dst, deg, E);
    k_scan1<<<nb1, blk, 0, stream>>>(deg, spart, bsum, N);
    k_scan2<<<1, 128, 0, stream>>>(bsum, nb1);
    k_scan3<<<gN, blk, 0, stream>>>(spart, bsum, rowptr, N);
    hipMemsetAsync(deg, 0, (size_t)N * sizeof(int), stream);  // reuse as fill
    if (packed)
        k_scatter<true><<<gE, blk, 0, stream>>>(src, dst, (const float4*)ea,
                                                rowptr, deg, rec, csr_src, E);
    else
        k_scatter<false><<<gE, blk, 0, stream>>>(src, dst, (const float4*)ea,
                                                 rowptr, deg, rec, csr_src, E);

    // ---- Layer 1 ----
    k_lin_tiled<16><<<gLin, blk, 0, stream>>>(x, Wl1, Wr1, A, B, N);
    if (packed)
        k_gat_agg<true><<<gAgg, blk, 0, stream>>>(rowptr, rec, csr_src, A, B,
                                                  We1, att1, b1, C, N, 1);
    else
        k_gat_agg<false><<<gAgg, blk, 0, stream>>>(rowptr, rec, csr_src, A, B,
                                                   We1, att1, b1, C, N, 1);

    // ---- Layer 2 ---- (xl2 -> B, xr2 -> A)
    k_lin_tiled<64><<<gLin, blk, 0, stream>>>(C, Wl2, Wr2, B, A, N);
    if (packed)
        k_gat_agg<true><<<gAgg, blk, 0, stream>>>(rowptr, rec, csr_src, B, A,
                                                  We2, att2, b2, C, N, 0);
    else
        k_gat_agg<false><<<gAgg, blk, 0, stream>>>(rowptr, rec, csr_src, B, A,
                                                   We2, att2, b2, C, N, 0);

    // ---- Pool + heads ----
    hipMemsetAsync(PL, 0, (4096 + 64) * sizeof(float), stream);
    k_pool<<<(N + 255) / 256, blk, 0, stream>>>(C, batch, PL, CT, N);
    k_head<<<64, 64, 0, stream>>>(PL, CT, Wg1, bg1, Wg2, bg2, Wp, bp,
                                  Wc1, bc1, Wc2, bc2, (float*)d_out);
}